// Round 13
// baseline (1266.940 us; speedup 1.0000x reference)
//
#include <hip/hip_runtime.h>
#include <math.h>

#define SRATE 32000.f
#define NB 128
#define NT 160000
#define CL 25             // samples per chunk (one chunk per thread)
#define TPB 256           // threads per block (4 waves)
#define TILEF (TPB*CL)    // 6400 floats per tile (25.6 KB)
#define TPR 25            // tiles per row (NT/TILEF)
#define NTILE (NB*TPR)    // 3200 total tiles  (r11/r12 bug: was 800)

// ws layout (disjoint; flags end at byte 16912 < Pb at byte 32768):
#define WS_FC   0         // float[15]
#define WS_GP   64        // float: GP[k] = Hc^(2^k), k=0..8 (324 floats)
#define WS_CNT  1024      // int: ticket counter
#define WS_FLAG 1028      // int[NTILE=3200] -> ints 1028..4227
#define WS_PBUF 8192      // float[NTILE*8]: inclusive prefix states

#ifndef M_PI
#define M_PI 3.14159265358979323846
#endif

// one cascade step; res <- y3 (pre-shift)
#define STEPR(xn, res) do { \
    float y1 = c[0]*(xn) + c[1]*x1  + c[2]*x2   - c[3]*y1p  - c[4]*y1pp;  \
    float y2 = c[5]*y1  + c[6]*y1p + c[7]*y1pp - c[8]*y2p  - c[9]*y2pp;   \
    float y3 = c[10]*y2 + c[11]*y2p + c[12]*y2pp - c[13]*y3p - c[14]*y3pp;\
    (res) = y3;                                                            \
    x2 = x1; x1 = (xn);                                                    \
    y1pp=y1p; y1p=y1; y2pp=y2p; y2p=y2; y3pp=y3p; y3p=y3;                  \
  } while (0)

// ---------------------------------------------------------------------------
// init: zero flags/counter; f64 coeffs (reference formula); Hc = M^CL and
// GP[k] = Hc^(2^k) for k=0..8. One block, 256 threads.
// ---------------------------------------------------------------------------
__global__ __launch_bounds__(256) void eq_init(
    const float* __restrict__ fr, const float* __restrict__ gn,
    const float* __restrict__ qs, float* __restrict__ ws)
{
  __shared__ double dc[24];
  __shared__ double Mb[36], Rb[36], Tb[36];
  const int t = threadIdx.x;
  int* wsi = (int*)ws;
  for (int i = t; i < NTILE; i += 256) wsi[WS_FLAG + i] = 0;
  if (t == 0) wsi[WS_CNT] = 0;
  if (t == 0) {
    for (int f = 0; f < 3; ++f) {
      double w0 = 2.0 * M_PI * (double)fr[f] / SRATE;
      double A  = exp((double)gn[f] / 40.0 * log(10.0));
      double al = sin(w0) / (2.0 * (double)qs[f]);
      double cw = cos(w0);
      double a0 = 1.0 + al / A;
      double b0 = (1.0 + al*A)/a0, b1 = -2.0*cw/a0, b2 = (1.0 - al*A)/a0;
      double A1 = -2.0*cw/a0,      A2 = (1.0 - al/A)/a0;
      dc[f*8+0]=b0; dc[f*8+1]=b1; dc[f*8+2]=b2; dc[f*8+3]=A1; dc[f*8+4]=A2;
      ws[WS_FC+f*5+0]=(float)b0; ws[WS_FC+f*5+1]=(float)b1; ws[WS_FC+f*5+2]=(float)b2;
      ws[WS_FC+f*5+3]=(float)A1; ws[WS_FC+f*5+4]=(float)A2;
    }
  }
  __syncthreads();
  if (t < 6) {   // one-step homogeneous matrix M, column t
    double s0=0,s1=0,s2=0,s3=0,s4=0,s5=0;
    if (t==0) s0=1; else if (t==1) s1=1; else if (t==2) s2=1;
    else if (t==3) s3=1; else if (t==4) s4=1; else s5=1;
    double y1 = -dc[3]*s0 - dc[4]*s1;
    double y2 = dc[8]*y1 + dc[9]*s0 + dc[10]*s1 - dc[11]*s2 - dc[12]*s3;
    double y3 = dc[16]*y2 + dc[17]*s2 + dc[18]*s3 - dc[19]*s4 - dc[20]*s5;
    Mb[0*6+t]=y1; Mb[1*6+t]=s0; Mb[2*6+t]=y2; Mb[3*6+t]=s2; Mb[4*6+t]=y3; Mb[5*6+t]=s4;
  }
  if (t < 36) Rb[t] = ((t % 7) == 0) ? 1.0 : 0.0;
  __syncthreads();
  const int i = t / 6, j = t % 6;
  int e = CL;                                 // Rb = M^CL = Hc
  while (e) {
    if (e & 1) {
      double acc = 0.0;
      if (t < 36) { for (int k = 0; k < 6; ++k) acc += Rb[i*6+k]*Mb[k*6+j]; Tb[t]=acc; }
      __syncthreads();
      if (t < 36) Rb[t] = Tb[t];
      __syncthreads();
    }
    e >>= 1;
    if (e) {
      double acc = 0.0;
      if (t < 36) { for (int k = 0; k < 6; ++k) acc += Mb[i*6+k]*Mb[k*6+j]; Tb[t]=acc; }
      __syncthreads();
      if (t < 36) Mb[t] = Tb[t];
      __syncthreads();
    }
  }
  if (t < 36) ws[WS_GP + t] = (float)Rb[t];   // GP[0] = Hc
  __syncthreads();
  for (int k = 1; k <= 8; ++k) {              // GP[k] = GP[k-1]^2
    double acc = 0.0;
    if (t < 36) { for (int m = 0; m < 6; ++m) acc += Rb[i*6+m]*Rb[m*6+j]; Tb[t]=acc; }
    __syncthreads();
    if (t < 36) Rb[t] = Tb[t];
    __syncthreads();
    if (t < 36) ws[WS_GP + k*36 + t] = (float)Rb[t];
    __syncthreads();
  }
}

// ---------------------------------------------------------------------------
// main: one tile per ticket. Tile lives in LDS through all phases: coop-load
// -> zero-state per-chunk IIR -> wave KS + cross-wave combine -> publish
// inclusive prefix (1-matvec chained hop per row) -> wait predecessor ->
// KS#2 with injected entry -> replay in LDS -> coop-store.
// x read ONCE, y written once. Chains: 25 deep per row, 128 rows parallel.
// ---------------------------------------------------------------------------
__global__ __launch_bounds__(TPB) void eq_m(
    const float* __restrict__ x, float* __restrict__ y,
    float* __restrict__ ws)
{
  __shared__ float lds[TILEF];
  __shared__ float Gl[9*36];
  __shared__ float fcl[16];
  __shared__ float wtot[4][8];
  __shared__ float sigma[8];
  __shared__ int s_t;
  const int tid = threadIdx.x, lane = tid & 63, w = tid >> 6;
  int* wsi = (int*)ws;
  int* flags = wsi + WS_FLAG;
  float* Pb = ws + WS_PBUF;

  if (tid == 0) s_t = atomicAdd(&wsi[WS_CNT], 1);
  for (int i = tid; i < 9*36; i += TPB) Gl[i] = ws[WS_GP + i];
  if (tid < 15) fcl[tid] = ws[WS_FC + tid];
  __syncthreads();
  const int t = s_t;
  const int ri = t % TPR;              // tile index within row
  float c[15];
  #pragma unroll
  for (int q = 0; q < 15; ++q) c[q] = fcl[q];

  // coop load tile (contiguous, coalesced): 1600 float4
  const float4* xp4 = (const float4*)(x + (size_t)t * TILEF);
  float4* l4 = (float4*)lds;
  #pragma unroll
  for (int it = 0; it < 6; ++it) l4[it*256 + tid] = xp4[it*256 + tid];
  if (tid < 64) l4[1536 + tid] = xp4[1536 + tid];
  __syncthreads();

  // per-chunk x-history (input data): previous 2 samples
  float bx1, bx2;
  if (tid == 0) {
    if (ri == 0) { bx1 = 0.f; bx2 = 0.f; }
    else { bx1 = x[(size_t)t*TILEF - 1]; bx2 = x[(size_t)t*TILEF - 2]; }
  } else {
    bx1 = lds[tid*CL - 1]; bx2 = lds[tid*CL - 2];
  }

  // ---- zero-entry-state IIR over own 25 samples -> e6 ----
  float e6[6];
  {
    float x1 = bx1, x2 = bx2;
    float y1p=0,y1pp=0,y2p=0,y2pp=0,y3p=0,y3pp=0;
    #pragma unroll
    for (int k = 0; k < CL; ++k) {
      float d_; STEPR(lds[tid*CL + k], d_); (void)d_;
    }
    e6[0]=y1p; e6[1]=y1pp; e6[2]=y2p; e6[3]=y2pp; e6[4]=y3p; e6[5]=y3pp;
  }

  // ---- Round A: wave-local Kogge-Stone (G[k] = Hc^(2^k)) ----
  float v6[6];
  #pragma unroll
  for (int q = 0; q < 6; ++q) v6[q] = e6[q];
  #pragma unroll
  for (int k = 0; k < 6; ++k) {
    const float* G = Gl + k*36;
    float o[6];
    #pragma unroll
    for (int q = 0; q < 6; ++q) o[q] = __shfl_up(v6[q], 1u << k, 64);
    if (lane >= (1 << k)) {
      float nv[6];
      #pragma unroll
      for (int q = 0; q < 6; ++q) {
        float a = v6[q];
        #pragma unroll
        for (int m = 0; m < 6; ++m) a += G[q*6+m]*o[m];
        nv[q] = a;
      }
      #pragma unroll
      for (int q = 0; q < 6; ++q) v6[q] = nv[q];
    }
  }
  if (lane == 63) {
    #pragma unroll
    for (int q = 0; q < 6; ++q) wtot[w][q] = v6[q];
  }
  __syncthreads();

  // ---- publisher (tid 0): tile total T, chained inclusive prefix ----
  const float* G6   = Gl + 6*36;   // Hc^64
  const float* H256 = Gl + 8*36;   // Hc^256
  if (tid == 0) {
    float T[6];
    #pragma unroll
    for (int q = 0; q < 6; ++q) T[q] = wtot[0][q];
    for (int ww = 1; ww < 4; ++ww) {
      float nT[6];
      #pragma unroll
      for (int q = 0; q < 6; ++q) {
        float a = wtot[ww][q];
        #pragma unroll
        for (int m = 0; m < 6; ++m) a += G6[q*6+m]*T[m];
        nT[q] = a;
      }
      #pragma unroll
      for (int q = 0; q < 6; ++q) T[q] = nT[q];
    }
    float sg[6] = {0,0,0,0,0,0};
    if (ri > 0) {
      while (__hip_atomic_load(&flags[t-1], __ATOMIC_ACQUIRE,
                               __HIP_MEMORY_SCOPE_AGENT) == 0)
        __builtin_amdgcn_s_sleep(4);
      const float* Pp = Pb + (size_t)(t-1)*8;
      #pragma unroll
      for (int q = 0; q < 6; ++q) sg[q] = Pp[q];
      float P[6];
      #pragma unroll
      for (int q = 0; q < 6; ++q) {
        float a = T[q];
        #pragma unroll
        for (int m = 0; m < 6; ++m) a += H256[q*6+m]*sg[m];
        P[q] = a;
      }
      #pragma unroll
      for (int q = 0; q < 6; ++q) Pb[(size_t)t*8 + q] = P[q];
    } else {
      #pragma unroll
      for (int q = 0; q < 6; ++q) Pb[(size_t)t*8 + q] = T[q];
    }
    __threadfence();
    __hip_atomic_store(&flags[t], 1, __ATOMIC_RELEASE, __HIP_MEMORY_SCOPE_AGENT);
    #pragma unroll
    for (int q = 0; q < 6; ++q) sigma[q] = sg[q];
  }
  __syncthreads();

  // ---- per-wave entry S_w = sigma evolved through preceding waves ----
  float S[6];
  #pragma unroll
  for (int q = 0; q < 6; ++q) S[q] = sigma[q];
  for (int ww = 0; ww < w; ++ww) {
    float nS[6];
    #pragma unroll
    for (int q = 0; q < 6; ++q) {
      float a = wtot[ww][q];
      #pragma unroll
      for (int m = 0; m < 6; ++m) a += G6[q*6+m]*S[m];
      nS[q] = a;
    }
    #pragma unroll
    for (int q = 0; q < 6; ++q) S[q] = nS[q];
  }

  // ---- Round B: KS with lane-0 entry injection (e0 += Hc*S_w) ----
  {
    if (lane == 0) {
      const float* Hc = Gl;       // GP[0]
      float ne[6];
      #pragma unroll
      for (int q = 0; q < 6; ++q) {
        float a = e6[q];
        #pragma unroll
        for (int m = 0; m < 6; ++m) a += Hc[q*6+m]*S[m];
        ne[q] = a;
      }
      #pragma unroll
      for (int q = 0; q < 6; ++q) e6[q] = ne[q];
    }
    #pragma unroll
    for (int q = 0; q < 6; ++q) v6[q] = e6[q];
    #pragma unroll
    for (int k = 0; k < 6; ++k) {
      const float* G = Gl + k*36;
      float o[6];
      #pragma unroll
      for (int q = 0; q < 6; ++q) o[q] = __shfl_up(v6[q], 1u << k, 64);
      if (lane >= (1 << k)) {
        float nv[6];
        #pragma unroll
        for (int q = 0; q < 6; ++q) {
          float a = v6[q];
          #pragma unroll
          for (int m = 0; m < 6; ++m) a += G[q*6+m]*o[m];
          nv[q] = a;
        }
        #pragma unroll
        for (int q = 0; q < 6; ++q) v6[q] = nv[q];
      }
    }
  }
  float en[6];
  #pragma unroll
  for (int q = 0; q < 6; ++q) en[q] = __shfl_up(v6[q], 1, 64);
  if (lane == 0) {
    #pragma unroll
    for (int q = 0; q < 6; ++q) en[q] = S[q];
  }

  // ---- replay with true entry; overwrite own LDS row with y ----
  {
    float x1 = bx1, x2 = bx2;
    float y1p=en[0], y1pp=en[1], y2p=en[2], y2pp=en[3], y3p=en[4], y3pp=en[5];
    #pragma unroll
    for (int k = 0; k < CL; ++k) {
      float o_;
      STEPR(lds[tid*CL + k], o_);
      lds[tid*CL + k] = o_;
    }
  }
  __syncthreads();

  // coop store tile -> y (coalesced)
  float4* yp4 = (float4*)(y + (size_t)t * TILEF);
  #pragma unroll
  for (int it = 0; it < 6; ++it) yp4[it*256 + tid] = l4[it*256 + tid];
  if (tid < 64) yp4[1536 + tid] = l4[1536 + tid];
}

extern "C" void kernel_launch(void* const* d_in, const int* in_sizes, int n_in,
                              void* d_out, int out_size, void* d_ws, size_t ws_size,
                              hipStream_t stream) {
  const float* clip = (const float*)d_in[0];
  const float* fr   = (const float*)d_in[1];
  const float* gn   = (const float*)d_in[2];
  const float* qs   = (const float*)d_in[3];
  float* out = (float*)d_out;
  float* ws  = (float*)d_ws;

  eq_init<<<1, 256, 0, stream>>>(fr, gn, qs, ws);
  eq_m<<<NTILE, TPB, 0, stream>>>(clip, out, ws);
}

// Round 14
// 80.250 us; speedup vs baseline: 15.7874x; 15.7874x over previous
//
#include <hip/hip_runtime.h>
#include <math.h>

#define SRATE 32000.f
#define NB 128            // batch rows
#define NT 160000         // samples per row
#define CL 50             // samples per chunk (one per thread)
#define TPB 128           // threads per block (2 waves) in eq_a/eq_c
#define NCROW 3200        // chunks per row
#define BPR 25            // blocks per row (NCROW/TPB)
#define NBLK (NB*BPR)     // 3200 blocks
#define SEG 50            // chunks per lane in eq_b scan (NCROW/64)
#define TILEF (TPB*CL)    // 6400 floats per tile (25.6 KB)
#define RECROW (NCROW*8)  // floats per row in eoT/sgT (25600)

#ifndef M_PI
#define M_PI 3.14159265358979323846
#endif

// f32 coefficients, reference formula (hardware transcendentals).
__device__ __forceinline__ void coeffs_f32(
    const float* fr, const float* gn, const float* qs, float* c)
{
  #pragma unroll
  for (int f = 0; f < 3; ++f) {
    float w0 = 2.f * (float)M_PI * fr[f] / SRATE;
    float A  = expf(gn[f] * (2.302585093f / 40.f));   // 10^(g/40)
    float al = sinf(w0) / (2.f * qs[f]);
    float cw = cosf(w0);
    float a0 = 1.f + al / A;
    c[f*5+0] = (1.f + al*A) / a0;
    c[f*5+1] = -2.f * cw / a0;
    c[f*5+2] = (1.f - al*A) / a0;
    c[f*5+3] = -2.f * cw / a0;
    c[f*5+4] = (1.f - al/A) / a0;
  }
}

// one cascade step; res <- y3 (pre-shift)
#define STEPR(xn, res) do { \
    float y1 = c[0]*(xn) + c[1]*x1  + c[2]*x2   - c[3]*y1p  - c[4]*y1pp;  \
    float y2 = c[5]*y1  + c[6]*y1p + c[7]*y1pp - c[8]*y2p  - c[9]*y2pp;   \
    float y3 = c[10]*y2 + c[11]*y2p + c[12]*y2pp - c[13]*y3p - c[14]*y3pp;\
    (res) = y3;                                                            \
    x2 = x1; x1 = (xn);                                                    \
    y1pp=y1p; y1p=y1; y2pp=y2p; y2p=y2; y3pp=y3p; y3p=y3;                  \
  } while (0)

// Async stage of one wave's half-tile (3200 floats) via global_load_lds:
// 12 full 1KB calls + 1 half call (lanes 0-31). Linear LDS dest.
__device__ __forceinline__ void stage_half(
    const float* __restrict__ src0, float* dst0, int lane)
{
  const float* src = src0 + lane * 4;
  #pragma unroll
  for (int cc = 0; cc < 12; ++cc) {
    __builtin_amdgcn_global_load_lds(
        (const __attribute__((address_space(1))) void*)(src + cc*256),
        (__attribute__((address_space(3))) void*)(dst0 + cc*256), 16, 0, 0);
  }
  if (lane < 32) {
    __builtin_amdgcn_global_load_lds(
        (const __attribute__((address_space(1))) void*)(src + 12*256),
        (__attribute__((address_space(3))) void*)(dst0 + 12*256), 16, 0, 0);
  }
}

// Transposed record layout (both eoT and sgT), per row of 3200 chunks:
// record of chunk ci lives at ((ci%50)*64 + ci/50) * 8 floats.
// eq_b touches (jj*64 + l) -> fully coalesced read AND write.

// ---------------------------------------------------------------------------
// A: LDS-staged zero-entry-state cascade, one chunk per thread, 2 waves/block.
// ---------------------------------------------------------------------------
__global__ __launch_bounds__(TPB) void eq_a(
    const float* __restrict__ x, const float* __restrict__ fr,
    const float* __restrict__ gn, const float* __restrict__ qs,
    float* __restrict__ eoT)
{
  __shared__ float lds[TILEF];
  const int tid = threadIdx.x, lane = tid & 63, w = tid >> 6;
  const int t = blockIdx.x, row = t / BPR, bi = t % BPR;
  float c[15];
  coeffs_f32(fr, gn, qs, c);
  const float* base = x + (size_t)row * NT + bi * TILEF;
  stage_half(base + w*3200, &lds[w*3200], lane);
  __syncthreads();                        // vmcnt(0): tile ready
  const int ci = bi * TPB + tid;
  float bx1, bx2;
  if (tid == 0) {
    if (bi == 0) { bx1 = 0.f; bx2 = 0.f; }
    else { bx1 = base[-1]; bx2 = base[-2]; }
  } else {
    bx1 = lds[tid*CL - 1]; bx2 = lds[tid*CL - 2];
  }
  float x1 = bx1, x2 = bx2;
  float y1p=0,y1pp=0,y2p=0,y2pp=0,y3p=0,y3pp=0;
  #pragma unroll
  for (int k = 0; k < CL; ++k) {
    float d_; STEPR(lds[tid*CL + k], d_); (void)d_;
  }
  float* ep = eoT + (size_t)row * RECROW + ((size_t)((ci%50)*64 + ci/50))*8;
  float4 r0; r0.x=y1p; r0.y=y1pp; r0.z=y2p; r0.w=y2pp;
  float4 r1; r1.x=y3p; r1.y=y3pp; r1.z=0.f; r1.w=0.f;
  *(float4*)ep = r0; *(float4*)(ep+4) = r1;
}

// ---------------------------------------------------------------------------
// B: one 64-lane block per row. Prologue (f64): Hc = M^CL, Gs[k]=Hc^(SEG*2^k).
// Kogge-Stone over 3200 chunk-exits; coalesced transposed read AND write.
// (math verified r6; layouts now symmetric-transposed)
// ---------------------------------------------------------------------------
__global__ __launch_bounds__(64) void eq_b(
    const float* __restrict__ fr, const float* __restrict__ gn,
    const float* __restrict__ qs, const float* __restrict__ eoT,
    float* __restrict__ sgT)
{
  __shared__ double Mb[36], Rb[36], Tb[36];
  __shared__ float Hs[36], Gs[6*36];
  const int l = threadIdx.x, row = blockIdx.x;
  float c[15];
  coeffs_f32(fr, gn, qs, c);
  if (l < 6) {   // one-step homogeneous matrix M, column l
    double s0=0,s1=0,s2=0,s3=0,s4=0,s5=0;
    if (l==0) s0=1; else if (l==1) s1=1; else if (l==2) s2=1;
    else if (l==3) s3=1; else if (l==4) s4=1; else s5=1;
    double y1 = -(double)c[3]*s0 - (double)c[4]*s1;
    double y2 = (double)c[5]*y1 + (double)c[6]*s0 + (double)c[7]*s1
              - (double)c[8]*s2 - (double)c[9]*s3;
    double y3 = (double)c[10]*y2 + (double)c[11]*s2 + (double)c[12]*s3
              - (double)c[13]*s4 - (double)c[14]*s5;
    Mb[0*6+l]=y1; Mb[1*6+l]=s0; Mb[2*6+l]=y2; Mb[3*6+l]=s2; Mb[4*6+l]=y3; Mb[5*6+l]=s4;
  }
  if (l < 36) Rb[l] = ((l % 7) == 0) ? 1.0 : 0.0;
  __syncthreads();
  const int i = l / 6, j = l % 6;
  int e = CL;                                 // Rb = M^CL = Hc
  while (e) {
    if (e & 1) {
      double acc = 0.0;
      if (l < 36) { for (int k = 0; k < 6; ++k) acc += Rb[i*6+k]*Mb[k*6+j]; Tb[l]=acc; }
      __syncthreads();
      if (l < 36) Rb[l] = Tb[l];
      __syncthreads();
    }
    e >>= 1;
    if (e) {
      double acc = 0.0;
      if (l < 36) { for (int k = 0; k < 6; ++k) acc += Mb[i*6+k]*Mb[k*6+j]; Tb[l]=acc; }
      __syncthreads();
      if (l < 36) Mb[l] = Tb[l];
      __syncthreads();
    }
  }
  if (l < 36) { Hs[l] = (float)Rb[l]; Mb[l] = Rb[l]; }
  __syncthreads();
  if (l < 36) Rb[l] = ((l % 7) == 0) ? 1.0 : 0.0;
  __syncthreads();
  e = SEG;                                    // Rb = Hc^SEG
  while (e) {
    if (e & 1) {
      double acc = 0.0;
      if (l < 36) { for (int k = 0; k < 6; ++k) acc += Rb[i*6+k]*Mb[k*6+j]; Tb[l]=acc; }
      __syncthreads();
      if (l < 36) Rb[l] = Tb[l];
      __syncthreads();
    }
    e >>= 1;
    if (e) {
      double acc = 0.0;
      if (l < 36) { for (int k = 0; k < 6; ++k) acc += Mb[i*6+k]*Mb[k*6+j]; Tb[l]=acc; }
      __syncthreads();
      if (l < 36) Mb[l] = Tb[l];
      __syncthreads();
    }
  }
  if (l < 36) Gs[l] = (float)Rb[l];
  __syncthreads();
  for (int k = 1; k < 6; ++k) {               // Gs[k] = Gs[k-1]^2
    double acc = 0.0;
    if (l < 36) { for (int m = 0; m < 6; ++m) acc += Rb[i*6+m]*Rb[m*6+j]; Tb[l]=acc; }
    __syncthreads();
    if (l < 36) Rb[l] = Tb[l];
    __syncthreads();
    if (l < 36) Gs[k*36+l] = (float)Rb[l];
    __syncthreads();
  }

  float H[36];
  #pragma unroll
  for (int q = 0; q < 36; ++q) H[q] = Hs[q];
  const float* rbase = eoT + (size_t)row * RECROW;
  float u[6] = {0,0,0,0,0,0};
  for (int jj = 0; jj < SEG; ++jj) {          // local zero-entry scan
    const float* ep = rbase + ((size_t)jj*64 + l)*8;
    float4 r0 = *(const float4*)ep, r1 = *(const float4*)(ep+4);
    float ev[6] = {r0.x,r0.y,r0.z,r0.w,r1.x,r1.y};
    float nu[6];
    #pragma unroll
    for (int q = 0; q < 6; ++q) {
      float a = ev[q];
      #pragma unroll
      for (int m = 0; m < 6; ++m) a += H[q*6+m]*u[m];
      nu[q] = a;
    }
    #pragma unroll
    for (int q = 0; q < 6; ++q) u[q] = nu[q];
  }
  float v6[6];
  #pragma unroll
  for (int q = 0; q < 6; ++q) v6[q] = u[q];
  #pragma unroll
  for (int k = 0; k < 6; ++k) {               // Kogge-Stone
    const float* G = Gs + k*36;
    float o[6];
    #pragma unroll
    for (int q = 0; q < 6; ++q) o[q] = __shfl_up(v6[q], 1u << k, 64);
    if (l >= (1 << k)) {
      float nv[6];
      #pragma unroll
      for (int q = 0; q < 6; ++q) {
        float a = v6[q];
        #pragma unroll
        for (int m = 0; m < 6; ++m) a += G[q*6+m]*o[m];
        nv[q] = a;
      }
      #pragma unroll
      for (int q = 0; q < 6; ++q) v6[q] = nv[q];
    }
  }
  float s[6];
  #pragma unroll
  for (int q = 0; q < 6; ++q) s[q] = __shfl_up(v6[q], 1, 64);
  if (l == 0) {
    #pragma unroll
    for (int q = 0; q < 6; ++q) s[q] = 0.f;
  }
  float* wbase = sgT + (size_t)row * RECROW;
  for (int jj = 0; jj < SEG; ++jj) {          // replay: entries, coalesced
    const float* ep = rbase + ((size_t)jj*64 + l)*8;
    float4 r0 = *(const float4*)ep, r1 = *(const float4*)(ep+4);
    float ev[6] = {r0.x,r0.y,r0.z,r0.w,r1.x,r1.y};
    float* wp = wbase + ((size_t)jj*64 + l)*8;   // chunk ci=l*SEG+jj, transposed
    float4 w0; w0.x=s[0]; w0.y=s[1]; w0.z=s[2]; w0.w=s[3];
    float4 w1; w1.x=s[4]; w1.y=s[5]; w1.z=0.f; w1.w=0.f;
    *(float4*)wp = w0; *(float4*)(wp+4) = w1;
    float ns[6];
    #pragma unroll
    for (int q = 0; q < 6; ++q) {
      float a = ev[q];
      #pragma unroll
      for (int m = 0; m < 6; ++m) a += H[q*6+m]*s[m];
      ns[q] = a;
    }
    #pragma unroll
    for (int q = 0; q < 6; ++q) s[q] = ns[q];
  }
}

// ---------------------------------------------------------------------------
// C: LDS-staged exact cascade with true entry state (transposed gather);
// in-place y in LDS, coop-store coalesced. 2 waves/block.
// ---------------------------------------------------------------------------
__global__ __launch_bounds__(TPB) void eq_c(
    const float* __restrict__ x, const float* __restrict__ fr,
    const float* __restrict__ gn, const float* __restrict__ qs,
    const float* __restrict__ sgT, float* __restrict__ y)
{
  __shared__ float lds[TILEF];
  const int tid = threadIdx.x, lane = tid & 63, w = tid >> 6;
  const int t = blockIdx.x, row = t / BPR, bi = t % BPR;
  float c[15];
  coeffs_f32(fr, gn, qs, c);
  const float* base = x + (size_t)row * NT + bi * TILEF;
  stage_half(base + w*3200, &lds[w*3200], lane);
  __syncthreads();                        // vmcnt(0): tile ready
  const int ci = bi * TPB + tid;
  float bx1, bx2;
  if (tid == 0) {
    if (bi == 0) { bx1 = 0.f; bx2 = 0.f; }
    else { bx1 = base[-1]; bx2 = base[-2]; }
  } else {
    bx1 = lds[tid*CL - 1]; bx2 = lds[tid*CL - 2];
  }
  const float* sp = sgT + (size_t)row * RECROW
                  + ((size_t)((ci%50)*64 + ci/50))*8;
  float4 s0 = *(const float4*)sp, s1 = *(const float4*)(sp+4);
  __syncthreads();                        // history reads done before overwrite
  float x1 = bx1, x2 = bx2;
  float y1p=s0.x, y1pp=s0.y, y2p=s0.z, y2pp=s0.w, y3p=s1.x, y3pp=s1.y;
  float* myrow = &lds[tid * CL];
  #pragma unroll
  for (int k = 0; k < CL; ++k) {
    float o_;
    STEPR(myrow[k], o_);
    myrow[k] = o_;                        // in-place y
  }
  __syncthreads();
  float* yg = y + (size_t)row * NT + bi * TILEF;
  const float4* l4 = (const float4*)lds;
  float4* yg4 = (float4*)yg;
  #pragma unroll
  for (int it = 0; it < 12; ++it)         // coalesced: 2KB contiguous/instr
    yg4[it*TPB + tid] = l4[it*TPB + tid];
  if (tid < 64) yg4[1536 + tid] = l4[1536 + tid];
}

// ws: eoT [0, 13.1MB) | sgT [13.1MB, 26.2MB)
extern "C" void kernel_launch(void* const* d_in, const int* in_sizes, int n_in,
                              void* d_out, int out_size, void* d_ws, size_t ws_size,
                              hipStream_t stream) {
  const float* clip = (const float*)d_in[0];
  const float* fr   = (const float*)d_in[1];
  const float* gn   = (const float*)d_in[2];
  const float* qs   = (const float*)d_in[3];
  float* out = (float*)d_out;
  float* eoT = (float*)d_ws;
  float* sgT = eoT + (size_t)NB * RECROW;

  eq_a<<<NBLK, TPB, 0, stream>>>(clip, fr, gn, qs, eoT);
  eq_b<<<NB, 64, 0, stream>>>(fr, gn, qs, eoT, sgT);
  eq_c<<<NBLK, TPB, 0, stream>>>(clip, fr, gn, qs, sgT, out);
}